// Round 5
// baseline (203.506 us; speedup 1.0000x reference)
//
#include <hip/hip_runtime.h>
#include <hip/hip_bf16.h>

// SchNet CFConv, MI355X gfx950 — round 5 (bisect round).
// Round 4 failed (absmax 0.92). New pieces in r4 were (a) ballot neighbor
// compaction, (b) merged prep+in2f K1. This round: round-3 cfconv VERBATIM
// (proven at 112 us) + round-4 K1. Pass -> compaction was the bug.
//
// d_ws layout (unsigned short elements):
//   [0     .. 4096 )  W1T bf16 [128 f][32 gpad]
//   [4096  .. 20480)  W2T bf16 [128 h][128 j]
//   [20480 .. +1.28M) yfeatb bf16 [10000][128]

#define NA 10000
#define NK 48
#define NF 128
#define DREP 40   // dRe LDS row pad (bf16, 80 B rows, 16B-aligned frags)
#define HP   136  // H   LDS row pad (bf16, 272 B rows)
#define WIP  136  // WiT LDS row pad (bf16)

typedef __bf16 bf16x8 __attribute__((ext_vector_type(8)));
typedef float  f32x4  __attribute__((ext_vector_type(4)));

__device__ __forceinline__ unsigned short f2bs(float x) {
    return __builtin_bit_cast(unsigned short, (__bf16)x);
}
__device__ __forceinline__ float bs2f(unsigned short u) {
    return (float)__builtin_bit_cast(__bf16, u);
}
__device__ __forceinline__ float sspf(float v) {
    return fmaxf(v, 0.0f) + __logf(1.0f + __expf(-fabsf(v))) - 0.69314718056f;
}

// ---- K1: blocks 0..624: yfeatb = bf16(x @ W_in2f); blocks 625..704: weight prep ----
__global__ __launch_bounds__(256) void in2f_prep(
    const float* __restrict__ x,
    const float* __restrict__ Wi,
    const float* __restrict__ W1,
    const float* __restrict__ W2,
    unsigned short* __restrict__ wsb)
{
    const int blk = blockIdx.x;
    const int tid = threadIdx.x;

    if (blk >= 625) {                         // ---- weight prep: W1T, W2T ----
        int i = (blk - 625) * 256 + tid;      // 0 .. 20479
        if (i < 4096) {                       // W1T[f][g], g padded to 32
            int f = i >> 5, g = i & 31;
            wsb[i] = (g < 25) ? f2bs(W1[g * NF + f]) : (unsigned short)0;
        } else {                              // W2T[h][j] = W2[j][h]
            int j = i - 4096; int h = j >> 7, k2 = j & 127;
            wsb[i] = f2bs(W2[k2 * NF + h]);
        }
        return;
    }

    // ---- in2f: 16 rows per block ----
    __shared__ __align__(16) unsigned short s_wt[NF * WIP];  // WiT[f][i], 34.8 KB
    unsigned short* yfeatb = wsb + 20480;

    for (int idx = tid; idx < NF * 32; idx += 256) {
        int i = idx >> 5, f4 = (idx & 31) * 4;
        float4 v = *(const float4*)(Wi + i * NF + f4);
        s_wt[(f4 + 0) * WIP + i] = f2bs(v.x);
        s_wt[(f4 + 1) * WIP + i] = f2bs(v.y);
        s_wt[(f4 + 2) * WIP + i] = f2bs(v.z);
        s_wt[(f4 + 3) * WIP + i] = f2bs(v.w);
    }
    __syncthreads();

    const int w = tid >> 6;
    const int lane = tid & 63;
    const int r = lane & 15;
    const int q = lane >> 4;
    const int nt0 = w * 2;
    const int m0 = blk * 16;     // 625*16 = 10000 exactly, no bounds checks

    bf16x8 a[4];
    #pragma unroll
    for (int ks = 0; ks < 4; ++ks) {
        const float4* xp = (const float4*)(x + (size_t)(m0 + r) * NF + ks * 32 + q * 8);
        float4 v0 = xp[0], v1 = xp[1];
        a[ks][0]=(__bf16)v0.x; a[ks][1]=(__bf16)v0.y; a[ks][2]=(__bf16)v0.z; a[ks][3]=(__bf16)v0.w;
        a[ks][4]=(__bf16)v1.x; a[ks][5]=(__bf16)v1.y; a[ks][6]=(__bf16)v1.z; a[ks][7]=(__bf16)v1.w;
    }

    f32x4 acc[2];
    acc[0] = (f32x4){0.f,0.f,0.f,0.f};
    acc[1] = (f32x4){0.f,0.f,0.f,0.f};
    #pragma unroll
    for (int ks = 0; ks < 4; ++ks) {
        bf16x8 b0 = *(const bf16x8*)(&s_wt[((nt0    ) * 16 + r) * WIP + ks * 32 + q * 8]);
        bf16x8 b1 = *(const bf16x8*)(&s_wt[((nt0 + 1) * 16 + r) * WIP + ks * 32 + q * 8]);
        acc[0] = __builtin_amdgcn_mfma_f32_16x16x32_bf16(a[ks], b0, acc[0], 0, 0, 0);
        acc[1] = __builtin_amdgcn_mfma_f32_16x16x32_bf16(a[ks], b1, acc[1], 0, 0, 0);
    }
    #pragma unroll
    for (int t = 0; t < 2; ++t)
        #pragma unroll
        for (int reg = 0; reg < 4; ++reg)
            yfeatb[(size_t)(m0 + q * 4 + reg) * NF + (nt0 + t) * 16 + r] = f2bs(acc[t][reg]);
}

// ---- K2: cfconv (round-3 verbatim: no compaction) ----
__global__ __launch_bounds__(256) void cfconv_mfma(
    const float* __restrict__ dR,
    const float* __restrict__ dRe,
    const float* __restrict__ mask,
    const int*   __restrict__ nbr,
    const float* __restrict__ b1,
    const float* __restrict__ b2,
    const float* __restrict__ Wf2o,
    const float* __restrict__ bf2o,
    const unsigned short* __restrict__ W1T,
    const unsigned short* __restrict__ W2T,
    const unsigned short* __restrict__ yfeatb,
    float* __restrict__ out)
{
    __shared__ __align__(16) unsigned short s_dre[NK * DREP]; // 3840 B
    __shared__ __align__(16) unsigned short s_H[NK * HP];     // 13056 B
    __shared__ __align__(16) float s_y[NF];
    __shared__ __align__(16) float s_part[256];
    __shared__ float s_cm[NK];
    __shared__ int   s_nb[NK];

    const int tid = threadIdx.x;
    const int n = blockIdx.x;
    const int w = tid >> 6;
    const int lane = tid & 63;
    const int r = lane & 15;
    const int q = lane >> 4;
    const int nt0 = w * 2;

    // ---- staging ----
    {
        unsigned int* z = (unsigned int*)s_dre;
        for (int i = tid; i < NK * DREP / 2; i += 256) z[i] = 0u;
    }
    if (tid < NK) {
        float d = dR[n * NK + tid];
        float m = mask[n * NK + tid];
        s_cm[tid] = (d <= 5.0f) ? m : 0.0f;
        s_nb[tid] = nbr[n * NK + tid] * NF;
    }
    __syncthreads();
    {
        const float* dre = dRe + (size_t)n * (NK * 25);
        for (int i = tid; i < NK * 25; i += 256) {
            int k = i / 25;
            int g = i - k * 25;
            s_dre[k * DREP + g] = f2bs(dre[i]);
        }
    }
    __syncthreads();

    // ---- stage 1: H = ssp(dRe @ W1 + b1) ----
    const float bias1a = b1[nt0 * 16 + r];
    const float bias1b = b1[nt0 * 16 + 16 + r];
    {
        bf16x8 bfr[2];
        bfr[0] = *(const bf16x8*)(W1T + ((nt0    ) * 16 + r) * 32 + q * 8);
        bfr[1] = *(const bf16x8*)(W1T + ((nt0 + 1) * 16 + r) * 32 + q * 8);
        #pragma unroll
        for (int mt = 0; mt < 3; ++mt) {
            bf16x8 a = *(const bf16x8*)(&s_dre[(mt * 16 + r) * DREP + q * 8]);
            #pragma unroll
            for (int t = 0; t < 2; ++t) {
                f32x4 zf; zf[0]=0.f; zf[1]=0.f; zf[2]=0.f; zf[3]=0.f;
                f32x4 h = __builtin_amdgcn_mfma_f32_16x16x32_bf16(a, bfr[t], zf, 0, 0, 0);
                float bia = t ? bias1b : bias1a;
                #pragma unroll
                for (int reg = 0; reg < 4; ++reg) {
                    int k = mt * 16 + q * 4 + reg;
                    int f = (nt0 + t) * 16 + r;
                    s_H[k * HP + f] = f2bs(sspf(h[reg] + bia));
                }
            }
        }
    }
    __syncthreads();

    // ---- stage 2: A2 = H @ W2 (bias in epilogue) ----
    const float bias2a = b2[nt0 * 16 + r];
    const float bias2b = b2[nt0 * 16 + 16 + r];
    f32x4 acc[3][2];
    #pragma unroll
    for (int mt = 0; mt < 3; ++mt)
        #pragma unroll
        for (int t = 0; t < 2; ++t) { acc[mt][t][0]=0.f; acc[mt][t][1]=0.f; acc[mt][t][2]=0.f; acc[mt][t][3]=0.f; }

    bf16x8 bw[2][4];
    #pragma unroll
    for (int t = 0; t < 2; ++t)
        #pragma unroll
        for (int ks = 0; ks < 4; ++ks)
            bw[t][ks] = *(const bf16x8*)(W2T + ((nt0 + t) * 16 + r) * NF + ks * 32 + q * 8);

    #pragma unroll
    for (int ks = 0; ks < 4; ++ks) {
        #pragma unroll
        for (int mt = 0; mt < 3; ++mt) {
            bf16x8 a = *(const bf16x8*)(&s_H[(mt * 16 + r) * HP + ks * 32 + q * 8]);
            #pragma unroll
            for (int t = 0; t < 2; ++t)
                acc[mt][t] = __builtin_amdgcn_mfma_f32_16x16x32_bf16(a, bw[t][ks], acc[mt][t], 0, 0, 0);
        }
    }

    // ---- gather + masked aggregation over neighbors ----
    float part0 = 0.f, part1 = 0.f;
    const int h0 = nt0 * 16 + r;
    #pragma unroll
    for (int mt = 0; mt < 3; ++mt) {
        #pragma unroll
        for (int reg = 0; reg < 4; ++reg) {
            int k = mt * 16 + q * 4 + reg;
            float cmk = s_cm[k];
            int base = s_nb[k];
            part0 += cmk * (acc[mt][0][reg] + bias2a) * bs2f(yfeatb[base + h0]);
            part1 += cmk * (acc[mt][1][reg] + bias2b) * bs2f(yfeatb[base + h0 + 16]);
        }
    }
    part0 += __shfl_xor(part0, 16);
    part0 += __shfl_xor(part0, 32);
    part1 += __shfl_xor(part1, 16);
    part1 += __shfl_xor(part1, 32);
    if (q == 0) {
        s_y[h0] = part0;
        s_y[h0 + 16] = part1;
    }
    __syncthreads();

    // ---- f2out: out = ssp(y @ Wf2o + b), split i-range over 2 half-blocks ----
    {
        int f = tid & 127;
        int half = tid >> 7;
        float o = 0.f;
        const float* wp = Wf2o + (size_t)(half * 64) * NF + f;
        const float* yp = s_y + half * 64;
        #pragma unroll 8
        for (int i = 0; i < 64; ++i)
            o = fmaf(yp[i], wp[(size_t)i * NF], o);
        s_part[tid] = o;
    }
    __syncthreads();
    if (tid < NF)
        out[(size_t)n * NF + tid] = sspf(s_part[tid] + s_part[tid + 128] + bf2o[tid]);
}

extern "C" void kernel_launch(void* const* d_in, const int* in_sizes, int n_in,
                              void* d_out, int out_size, void* d_ws, size_t ws_size,
                              hipStream_t stream)
{
    const float* x    = (const float*)d_in[0];
    const float* dR   = (const float*)d_in[1];
    const float* dRe  = (const float*)d_in[2];
    const float* mask = (const float*)d_in[3];
    const int*   nbr  = (const int*)d_in[4];
    const float* W1   = (const float*)d_in[5];
    const float* b1   = (const float*)d_in[6];
    const float* W2   = (const float*)d_in[7];
    const float* b2   = (const float*)d_in[8];
    const float* Wi2f = (const float*)d_in[9];
    const float* Wf2o = (const float*)d_in[10];
    const float* bf2o = (const float*)d_in[11];
    float* out = (float*)d_out;

    unsigned short* wsb = (unsigned short*)d_ws;
    unsigned short* W1T    = wsb;            // 4096 elems
    unsigned short* W2T    = wsb + 4096;     // 16384 elems
    unsigned short* yfeatb = wsb + 20480;    // 1,280,000 elems

    in2f_prep<<<705, 256, 0, stream>>>(x, Wi2f, W1, W2, wsb);
    cfconv_mfma<<<NA, 256, 0, stream>>>(dR, dRe, mask, nbr, b1, b2, Wf2o, bf2o,
                                        W1T, W2T, yfeatb, out);
}